// Round 8
// baseline (166.568 us; speedup 1.0000x reference)
//
#include <hip/hip_runtime.h>

#define D_ 64
#define L_ 50
#define B_ 4096
#define T_ 100
#define SP 65    // f32 gi buffer stride
#define RS 72    // bf16 eb row stride (144 B, 16B-aligned for b128)

typedef __attribute__((ext_vector_type(8))) short  short8;   // 8 bf16 = 4 VGPRs
typedef __attribute__((ext_vector_type(4))) float  float4v;  // MFMA acc
typedef __attribute__((ext_vector_type(4))) unsigned short ushort4v;

__device__ __forceinline__ float sigmoidf_(float x) {
    return 1.0f / (1.0f + __expf(-x));
}
__device__ __forceinline__ unsigned short f2bf(float x) {   // RNE f32->bf16
    unsigned u = __builtin_bit_cast(unsigned, x);
    return (unsigned short)((u + 0x7fffu + ((u >> 16) & 1u)) >> 16);
}
__device__ __forceinline__ float bf2f(unsigned short s) {
    return __builtin_bit_cast(float, (unsigned)s << 16);
}

// Prep 1: table f32 -> bf16 (streaming, float4 -> ushort4)
__global__ __launch_bounds__(256) void hgn_cvt_bf16(
    const float4* __restrict__ src, ushort4v* __restrict__ dst, int n4)
{
    const int i = blockIdx.x * 256 + threadIdx.x;
    if (i < n4) {
        const float4 r = src[i];
        ushort4v o = { f2bf(r.x), f2bf(r.y), f2bf(r.z), f2bf(r.w) };
        dst[i] = o;
    }
}

// Prep 2: wbT[c*64+k] = bf16(W[k][c])
__global__ __launch_bounds__(256) void hgn_transpose_w(
    const float* __restrict__ fg_item_W, unsigned short* __restrict__ wbT)
{
    const int i = blockIdx.x * 256 + threadIdx.x;   // i over 4096
    const int k = i >> 6, c = i & 63;
    wbT[c * 64 + k] = f2bf(fg_item_W[i]);
}

// Main: one block (4 waves) per batch b. bf16 gathers + early W2 reg prefetch.
__global__ __launch_bounds__(256) void hgn_fused_main(
    const int* __restrict__ item_seq,          // [B,L]
    const int* __restrict__ user_ids,          // [B]
    const int* __restrict__ items_to_predict,  // [B,T]
    const float* __restrict__ user_emb_table,  // [U,D] f32
    const unsigned short* __restrict__ ebf,    // [I,D] bf16 item table
    const unsigned short* __restrict__ wbT,    // [64,64] bf16 W^T
    const float* __restrict__ fg_item_b,       // [D]
    const float* __restrict__ fg_user_W,       // [D,D]
    const float* __restrict__ fg_user_b,       // [D]
    const float* __restrict__ ig_item,         // [D]
    const float* __restrict__ ig_user,         // [D,L]
    const unsigned short* __restrict__ w2bf,   // [I,D] bf16 W2
    const float* __restrict__ b2,              // [I]
    float* __restrict__ out)                   // [B,T]
{
    __shared__ unsigned short eb_sh[64 * RS];   // E rows bf16 (rows>=50 garbage ok)
    __shared__ float part_sh[L_ * SP];          // gi
    __shared__ __align__(16) float u_sh[D_];
    __shared__ __align__(16) float v_sh[D_];
    __shared__ float gb_sh[D_];
    __shared__ float s_sh[L_];
    __shared__ float bp_sh[2][64];
    __shared__ float esum_sh[D_];

    const int t    = threadIdx.x;
    const int lane = t & 63;
    const int wave = t >> 6;
    const int b    = blockIdx.x;

    // ---- Early W2 prefetch: threads 0..199 hold one bf16 half-row (16 VGPRs)
    short8 w2r0, w2r1, w2r2, w2r3;
    float b2v = 0.f;
    const int tt = t >> 1, half = t & 1;
    if (t < 2 * T_) {
        const int idxp = items_to_predict[b * T_ + tt];
        const unsigned short* wr = w2bf + (size_t)idxp * D_ + half * 32;
        w2r0 = *(const short8*)(wr + 0);
        w2r1 = *(const short8*)(wr + 8);
        w2r2 = *(const short8*)(wr + 16);
        w2r3 = *(const short8*)(wr + 24);
        b2v  = b2[idxp];
    }

    if (wave == 3) {
        // u + gbias (same-wave LDS visibility, no barrier needed inside)
        const int uid = user_ids[b];
        u_sh[lane] = user_emb_table[(size_t)uid * D_ + lane];
        float g0 = fg_item_b[lane], g1 = fg_user_b[lane], g2 = 0.f, g3 = 0.f;
#pragma unroll
        for (int k = 0; k < D_; k += 4) {
            g0 = fmaf(u_sh[k + 0], fg_user_W[(k + 0) * D_ + lane], g0);
            g1 = fmaf(u_sh[k + 1], fg_user_W[(k + 1) * D_ + lane], g1);
            g2 = fmaf(u_sh[k + 2], fg_user_W[(k + 2) * D_ + lane], g2);
            g3 = fmaf(u_sh[k + 3], fg_user_W[(k + 3) * D_ + lane], g3);
        }
        gb_sh[lane] = (g0 + g1) + (g2 + g3);
    } else {
        // waves 0-2: stage E bf16 rows. i over 400 16B-chunks; own idx loads.
        const int i0 = t, i1 = t + 192, i2 = t + 384;
        const int id0 = item_seq[b * L_ + (i0 >> 3)];
        const int id1 = item_seq[b * L_ + (i1 >> 3)];
        const int id2 = (i2 < 400) ? item_seq[b * L_ + (i2 >> 3)] : 0;
        const short8 r0 = *(const short8*)(ebf + (size_t)id0 * D_ + (i0 & 7) * 8);
        const short8 r1 = *(const short8*)(ebf + (size_t)id1 * D_ + (i1 & 7) * 8);
        short8 r2;
        if (i2 < 400) r2 = *(const short8*)(ebf + (size_t)id2 * D_ + (i2 & 7) * 8);
        *(short8*)&eb_sh[(i0 >> 3) * RS + (i0 & 7) * 8] = r0;
        *(short8*)&eb_sh[(i1 >> 3) * RS + (i1 & 7) * 8] = r1;
        if (i2 < 400) *(short8*)&eb_sh[(i2 >> 3) * RS + (i2 & 7) * 8] = r2;
    }
    __syncthreads();   // eb / u / gb ready

    // ---- MFMA gate matmul + fused finalize. Wave w -> P rows [16w,16w+16).
    {
        const int m = lane & 15, q = lane >> 4;
        const int arow = 16 * wave + m;
        const short8 a0 = *(const short8*)&eb_sh[arow * RS + q * 8];
        const short8 a1 = *(const short8*)&eb_sh[arow * RS + 32 + q * 8];
#pragma unroll
        for (int n = 0; n < 4; ++n) {
            const int col = 16 * n + m;
            const short8 b0 = *(const short8*)&wbT[col * 64 + q * 8];
            const short8 b1 = *(const short8*)&wbT[col * 64 + 32 + q * 8];
            float4v acc = {0.f, 0.f, 0.f, 0.f};
            acc = __builtin_amdgcn_mfma_f32_16x16x32_bf16(a0, b0, acc, 0, 0, 0);
            acc = __builtin_amdgcn_mfma_f32_16x16x32_bf16(a1, b1, acc, 0, 0, 0);
            const float gbc = gb_sh[col];
#pragma unroll
            for (int r = 0; r < 4; ++r) {
                const int l = 16 * wave + q * 4 + r;   // C/D: row=q*4+r, col
                if (l < L_) {
                    const float e = bf2f(eb_sh[l * RS + col]);
                    part_sh[l * SP + col] = e * sigmoidf_(acc[r] + gbc);
                }
            }
        }
    }
    __syncthreads();   // gi ready

    // ---- Phase B partials (waves 0,1: d-halves) + esum (wave 2)
    if (wave < 2) {
        if (lane < L_) {
            const int d0 = 32 * wave;
            float p0 = 0.f, p1 = 0.f, p2 = 0.f, p3 = 0.f;
#pragma unroll
            for (int j = 0; j < 32; j += 4) {
                const int d = d0 + j;
                p0 = fmaf(part_sh[lane * SP + d + 0], ig_item[d + 0], p0);
                p1 = fmaf(part_sh[lane * SP + d + 1], ig_item[d + 1], p1);
                p2 = fmaf(part_sh[lane * SP + d + 2], ig_item[d + 2], p2);
                p3 = fmaf(part_sh[lane * SP + d + 3], ig_item[d + 3], p3);
                p0 = fmaf(u_sh[d + 0], ig_user[(d + 0) * L_ + lane], p0);
                p1 = fmaf(u_sh[d + 1], ig_user[(d + 1) * L_ + lane], p1);
                p2 = fmaf(u_sh[d + 2], ig_user[(d + 2) * L_ + lane], p2);
                p3 = fmaf(u_sh[d + 3], ig_user[(d + 3) * L_ + lane], p3);
            }
            bp_sh[wave][lane] = (p0 + p1) + (p2 + p3);
        }
    } else if (wave == 2) {
        float e0 = 0.f, e1 = 0.f;
#pragma unroll
        for (int l = 0; l < L_; l += 2) {
            e0 += bf2f(eb_sh[l * RS + lane]);
            e1 += bf2f(eb_sh[(l + 1) * RS + lane]);
        }
        esum_sh[lane] = e0 + e1;
    }
    __syncthreads();   // bp / esum ready

    // ---- Phase C: wave 0
    if (wave == 0) {
        if (lane < L_) s_sh[lane] = sigmoidf_(bp_sh[0][lane] + bp_sh[1][lane]);
        float a0 = 0.f, a1 = 0.f, ss = 0.f;
        for (int l = 0; l < L_; l += 2) {
            const float sA = s_sh[l], sB = s_sh[l + 1];
            a0 = fmaf(part_sh[l * SP + lane], sA, a0);
            a1 = fmaf(part_sh[(l + 1) * SP + lane], sB, a1);
            ss += sA + sB;
        }
        v_sh[lane] = u_sh[lane] + (a0 + a1) / ss + esum_sh[lane];
    }
    __syncthreads();   // v_sh ready

    // ---- Phase D: consume prefetched W2 regs
    if (t < 2 * T_) {
        const float* vh = v_sh + half * 32;
        float a0 = 0.f, a1 = 0.f, a2 = 0.f, a3 = 0.f;
#pragma unroll
        for (int j = 0; j < 8; ++j) {
            a0 = fmaf(bf2f((unsigned short)w2r0[j]), vh[j + 0],  a0);
            a1 = fmaf(bf2f((unsigned short)w2r1[j]), vh[j + 8],  a1);
            a2 = fmaf(bf2f((unsigned short)w2r2[j]), vh[j + 16], a2);
            a3 = fmaf(bf2f((unsigned short)w2r3[j]), vh[j + 24], a3);
        }
        float r = (a0 + a1) + (a2 + a3);
        r += __shfl_xor(r, 1, 64);
        if (half == 0) out[b * T_ + tt] = r + b2v;
    }
}

// ---------------- Fallback (R7 structure, needs only 8 KB ws) ----------------
__global__ __launch_bounds__(256) void hgn_fused_fallback(
    const int* __restrict__ item_seq, const int* __restrict__ user_ids,
    const int* __restrict__ items_to_predict,
    const float* __restrict__ user_emb_table, const float* __restrict__ item_emb_table,
    const unsigned short* __restrict__ wbT, const float* __restrict__ fg_item_b,
    const float* __restrict__ fg_user_W, const float* __restrict__ fg_user_b,
    const float* __restrict__ ig_item, const float* __restrict__ ig_user,
    const float* __restrict__ W2, const float* __restrict__ b2,
    float* __restrict__ out)
{
    __shared__ unsigned short eb_sh[64 * RS];
    __shared__ float part_sh[L_ * SP];
    __shared__ __align__(16) float u_sh[D_];
    __shared__ __align__(16) float v_sh[D_];
    __shared__ float gb_sh[D_];
    __shared__ float s_sh[L_];
    __shared__ float bp_sh[2][64];
    __shared__ float esum_sh[D_];
    __shared__ int   idx_sh[L_];

    const int t = threadIdx.x, lane = t & 63, wave = t >> 6, b = blockIdx.x;

    if (t < L_) idx_sh[t] = item_seq[b * L_ + t];
    if (t >= 64 && t < 128) {
        const int uid = user_ids[b];
        u_sh[t - 64] = user_emb_table[(size_t)uid * D_ + (t - 64)];
    }
    __syncthreads();
    if (wave == 3) {
        float g0 = fg_item_b[lane], g1 = fg_user_b[lane], g2 = 0.f, g3 = 0.f;
#pragma unroll
        for (int k = 0; k < D_; k += 4) {
            g0 = fmaf(u_sh[k + 0], fg_user_W[(k + 0) * D_ + lane], g0);
            g1 = fmaf(u_sh[k + 1], fg_user_W[(k + 1) * D_ + lane], g1);
            g2 = fmaf(u_sh[k + 2], fg_user_W[(k + 2) * D_ + lane], g2);
            g3 = fmaf(u_sh[k + 3], fg_user_W[(k + 3) * D_ + lane], g3);
        }
        gb_sh[lane] = (g0 + g1) + (g2 + g3);
    } else {
        for (int i = t; i < L_ * 16; i += 192) {
            const int l = i >> 4, qd = i & 15;
            const float4 r = ((const float4*)(item_emb_table + (size_t)idx_sh[l] * D_))[qd];
            ushort4v o = { f2bf(r.x), f2bf(r.y), f2bf(r.z), f2bf(r.w) };
            *(ushort4v*)&eb_sh[l * RS + qd * 4] = o;
        }
    }
    __syncthreads();
    {
        const int m = lane & 15, q = lane >> 4;
        const int arow = 16 * wave + m;
        const short8 a0 = *(const short8*)&eb_sh[arow * RS + q * 8];
        const short8 a1 = *(const short8*)&eb_sh[arow * RS + 32 + q * 8];
#pragma unroll
        for (int n = 0; n < 4; ++n) {
            const int col = 16 * n + m;
            const short8 b0 = *(const short8*)&wbT[col * 64 + q * 8];
            const short8 b1 = *(const short8*)&wbT[col * 64 + 32 + q * 8];
            float4v acc = {0.f, 0.f, 0.f, 0.f};
            acc = __builtin_amdgcn_mfma_f32_16x16x32_bf16(a0, b0, acc, 0, 0, 0);
            acc = __builtin_amdgcn_mfma_f32_16x16x32_bf16(a1, b1, acc, 0, 0, 0);
            const float gbc = gb_sh[col];
#pragma unroll
            for (int r = 0; r < 4; ++r) {
                const int l = 16 * wave + q * 4 + r;
                if (l < L_) {
                    const float e = bf2f(eb_sh[l * RS + col]);
                    part_sh[l * SP + col] = e * sigmoidf_(acc[r] + gbc);
                }
            }
        }
    }
    __syncthreads();
    if (wave < 2) {
        if (lane < L_) {
            const int d0 = 32 * wave;
            float p0 = 0.f, p1 = 0.f, p2 = 0.f, p3 = 0.f;
#pragma unroll
            for (int j = 0; j < 32; j += 4) {
                const int d = d0 + j;
                p0 = fmaf(part_sh[lane * SP + d + 0], ig_item[d + 0], p0);
                p1 = fmaf(part_sh[lane * SP + d + 1], ig_item[d + 1], p1);
                p2 = fmaf(part_sh[lane * SP + d + 2], ig_item[d + 2], p2);
                p3 = fmaf(part_sh[lane * SP + d + 3], ig_item[d + 3], p3);
                p0 = fmaf(u_sh[d + 0], ig_user[(d + 0) * L_ + lane], p0);
                p1 = fmaf(u_sh[d + 1], ig_user[(d + 1) * L_ + lane], p1);
                p2 = fmaf(u_sh[d + 2], ig_user[(d + 2) * L_ + lane], p2);
                p3 = fmaf(u_sh[d + 3], ig_user[(d + 3) * L_ + lane], p3);
            }
            bp_sh[wave][lane] = (p0 + p1) + (p2 + p3);
        }
    } else if (wave == 2) {
        float e0 = 0.f, e1 = 0.f;
#pragma unroll
        for (int l = 0; l < L_; l += 2) {
            e0 += bf2f(eb_sh[l * RS + lane]);
            e1 += bf2f(eb_sh[(l + 1) * RS + lane]);
        }
        esum_sh[lane] = e0 + e1;
    }
    __syncthreads();
    if (wave == 0) {
        if (lane < L_) s_sh[lane] = sigmoidf_(bp_sh[0][lane] + bp_sh[1][lane]);
        float a0 = 0.f, a1 = 0.f, ss = 0.f;
        for (int l = 0; l < L_; l += 2) {
            const float sA = s_sh[l], sB = s_sh[l + 1];
            a0 = fmaf(part_sh[l * SP + lane], sA, a0);
            a1 = fmaf(part_sh[(l + 1) * SP + lane], sB, a1);
            ss += sA + sB;
        }
        v_sh[lane] = u_sh[lane] + (a0 + a1) / ss + esum_sh[lane];
    }
    __syncthreads();
    if (t < 2 * T_) {
        const int tt = t >> 1, half = t & 1;
        const int idx = items_to_predict[b * T_ + tt];
        const float* wrow  = W2 + (size_t)idx * D_ + half * 32;
        const float* vhalf = v_sh + half * 32;
        float r0 = 0.f, r1 = 0.f, r2 = 0.f, r3 = 0.f;
#pragma unroll
        for (int kk = 0; kk < 8; ++kk) {
            const float4 w4 = ((const float4*)wrow)[kk];
            const float4 v4 = ((const float4*)vhalf)[kk];
            r0 = fmaf(v4.x, w4.x, r0);
            r1 = fmaf(v4.y, w4.y, r1);
            r2 = fmaf(v4.z, w4.z, r2);
            r3 = fmaf(v4.w, w4.w, r3);
        }
        float r = (r0 + r1) + (r2 + r3);
        r += __shfl_xor(r, 1, 64);
        if (half == 0) out[b * T_ + tt] = r + b2[idx];
    }
}

extern "C" void kernel_launch(void* const* d_in, const int* in_sizes, int n_in,
                              void* d_out, int out_size, void* d_ws, size_t ws_size,
                              hipStream_t stream) {
    const int*   item_seq   = (const int*)d_in[0];
    const int*   user_ids   = (const int*)d_in[1];
    const int*   items_pred = (const int*)d_in[2];
    const float* uet        = (const float*)d_in[3];
    const float* iet        = (const float*)d_in[4];
    const float* fgiW       = (const float*)d_in[5];
    const float* fgib       = (const float*)d_in[6];
    const float* fguW       = (const float*)d_in[7];
    const float* fgub       = (const float*)d_in[8];
    const float* igi        = (const float*)d_in[9];
    const float* igu        = (const float*)d_in[10];
    const float* W2         = (const float*)d_in[11];
    const float* b2t        = (const float*)d_in[12];

    const size_t tbl_elems = 100000 * 64;                   // per table
    const size_t tbl_bytes = tbl_elems * 2;                 // 12.8 MB bf16
    const size_t need = 2 * tbl_bytes + 8192;

    if (ws_size >= need) {
        unsigned short* w2bf = (unsigned short*)d_ws;
        unsigned short* ebf  = (unsigned short*)((char*)d_ws + tbl_bytes);
        unsigned short* wbT  = (unsigned short*)((char*)d_ws + 2 * tbl_bytes);
        const int n4 = (int)(tbl_elems / 4);                // 1.6M float4s
        hgn_cvt_bf16<<<(n4 + 255) / 256, 256, 0, stream>>>(
            (const float4*)W2,  (ushort4v*)w2bf, n4);
        hgn_cvt_bf16<<<(n4 + 255) / 256, 256, 0, stream>>>(
            (const float4*)iet, (ushort4v*)ebf,  n4);
        hgn_transpose_w<<<16, 256, 0, stream>>>(fgiW, wbT);
        hgn_fused_main<<<B_, 256, 0, stream>>>(
            item_seq, user_ids, items_pred, uet, ebf, wbT,
            fgib, fguW, fgub, igi, igu, w2bf, b2t, (float*)d_out);
    } else {
        unsigned short* wbT = (unsigned short*)d_ws;        // 8 KB
        hgn_transpose_w<<<16, 256, 0, stream>>>(fgiW, wbT);
        hgn_fused_fallback<<<B_, 256, 0, stream>>>(
            item_seq, user_ids, items_pred, uet, iet,
            wbT, fgib, fguW, fgub, igi, igu, W2, b2t, (float*)d_out);
    }
}